// Round 10
// baseline (260.657 us; speedup 1.0000x reference)
//
#include <hip/hip_runtime.h>
#include <hip/hip_bf16.h>

// PrototypeConsistentLearning: loss = mean(-pos + lse_neg), new_protos = serial EMA.
// B=8192, D=512, K=16384, T=0.5, momentum=0.9.
// R16: NO-LDS flash. Books on the LDS family: LDS-read bytes = (8192/wave_M)*8MB
// (R14 1.05GB / R15 2.1GB, conflicts 4.2M/8.4M confirm) + ~8cy/read conflict tax
// -> LDS pipe 98-131k cy/CU vs 70k matrix: LDS always the long pole. And R15's
// occupancy never rose: grid 512 blocks = 2/CU capped TLP, not registers.
// Fix: B-frags stream from L2 straight into registers (16 rows x 128 B
// contiguous per frag = perfectly coalesced), XCD-pinned K-splits keep each
// XCD's 1 MB proq slice L2-resident. 1 GB L2 reads ~ 70k cy/CU == matrix pipe,
// on a different pipe, with ZERO barriers/staging/conflicts -- waves fully
// independent (the regime where setprio pays, m191). Named double-buffer bfA/bfB
// prefetches step s+1 under step s's 16 MFMAs; column-major full-K steps keep
// acc at 4 named floatx4. Regs: afr 128 + bf 64 + acc 16 + rs 16 + addr ~ 235
// < 256 -> 2 waves/SIMD, 8 async waves/CU (KSPLIT=16, 512 blocks x 4 waves).
// Same x16 e4m3 quantization; exp un-scale 2^-8. pos/EMA exact fp32, unchanged.

#define B_N 8192
#define D_N 512
#define K_N 16384
#define INV_T 2.0f
#define MOM 0.9f

#define KSPLIT 16       // each wave covers K_N/KSPLIT = 1024 proto rows
#define NSTEP 64        // 16-col steps per wave (1024 / 16)
#define CAP 64

typedef __attribute__((ext_vector_type(8))) int intx8;
typedef __attribute__((ext_vector_type(4))) float floatx4;

__device__ __forceinline__ floatx4 mxfma(intx8 a, intx8 b, floatx4 c) {
    return __builtin_amdgcn_mfma_scale_f32_16x16x128_f8f6f4(a, b, c, 0, 0, 0,
                                                            0x7F7F7F7F, 0, 0x7F7F7F7F);
}

// ---- normalize rows (fp32) -> e4m3 fp8 scaled by 16; also zero rowsum/out[0]. ----
__global__ void norm_kernel(const float* __restrict__ emb, const float* __restrict__ pro,
                            unsigned char* __restrict__ embq, unsigned char* __restrict__ proq,
                            float* __restrict__ rowsum, float* __restrict__ out) {
    if (blockIdx.x < 32) rowsum[blockIdx.x * 256 + threadIdx.x] = 0.0f;
    if (blockIdx.x == 32 && threadIdx.x == 0) out[0] = 0.0f;
    int row = blockIdx.x * 4 + (threadIdx.x >> 6);
    int lane = threadIdx.x & 63;
    const float* x;
    unsigned char* o;
    if (row < B_N) {
        x = emb + (size_t)row * D_N;
        o = embq + (size_t)row * D_N;
    } else {
        x = pro + (size_t)(row - B_N) * D_N;
        o = proq + (size_t)(row - B_N) * D_N;
    }
    const float4* xp = (const float4*)(x + lane * 8);
    float4 v0 = xp[0];
    float4 v1 = xp[1];
    float ss = v0.x * v0.x + v0.y * v0.y + v0.z * v0.z + v0.w * v0.w +
               v1.x * v1.x + v1.y * v1.y + v1.z * v1.z + v1.w * v1.w;
    #pragma unroll
    for (int of = 32; of; of >>= 1) ss += __shfl_xor(ss, of);
    float sc = 16.0f / fmaxf(sqrtf(ss), 1e-12f);  // x16: e4m3 keeps full mantissa range
    int w0 = 0, w1 = 0;
    w0 = __builtin_amdgcn_cvt_pk_fp8_f32(v0.x * sc, v0.y * sc, w0, false);
    w0 = __builtin_amdgcn_cvt_pk_fp8_f32(v0.z * sc, v0.w * sc, w0, true);
    w1 = __builtin_amdgcn_cvt_pk_fp8_f32(v1.x * sc, v1.y * sc, w1, false);
    w1 = __builtin_amdgcn_cvt_pk_fp8_f32(v1.z * sc, v1.w * sc, w1, true);
    int2 st = {w0, w1};
    *(int2*)(o + lane * 8) = st;
}

// ---- pos[b] = 2 * dot(emb[b],pro[c]) / (|emb[b]| |pro[c]|), pure fp32 (exact). ----
__global__ void pos_kernel(const float* __restrict__ emb, const float* __restrict__ pro,
                           const int* __restrict__ cid, float* __restrict__ rowpos) {
    int b = blockIdx.x * 4 + (threadIdx.x >> 6);
    int lane = threadIdx.x & 63;
    int c = cid[b];
    const float4* ep = (const float4*)(emb + (size_t)b * D_N + lane * 8);
    const float4* pp = (const float4*)(pro + (size_t)c * D_N + lane * 8);
    float4 e0 = ep[0], e1 = ep[1], p0 = pp[0], p1 = pp[1];
    float dp = e0.x * p0.x + e0.y * p0.y + e0.z * p0.z + e0.w * p0.w +
               e1.x * p1.x + e1.y * p1.y + e1.z * p1.z + e1.w * p1.w;
    float ee = e0.x * e0.x + e0.y * e0.y + e0.z * e0.z + e0.w * e0.w +
               e1.x * e1.x + e1.y * e1.y + e1.z * e1.z + e1.w * e1.w;
    float qq = p0.x * p0.x + p0.y * p0.y + p0.z * p0.z + p0.w * p0.w +
               p1.x * p1.x + p1.y * p1.y + p1.z * p1.z + p1.w * p1.w;
    #pragma unroll
    for (int o = 32; o; o >>= 1) {
        dp += __shfl_xor(dp, o);
        ee += __shfl_xor(ee, o);
        qq += __shfl_xor(qq, o);
    }
    if (lane == 0)
        rowpos[b] = INV_T * dp / (fmaxf(sqrtf(ee), 1e-12f) * fmaxf(sqrtf(qq), 1e-12f));
}

// Load the 4 B chunk-frags for 16-col step S into named buffer BUF (8 dwordx4
// from L2; per frag: 16 rows x 128 B contiguous segments, fully coalesced).
#define LOADB(BUF, S)                                                                 \
    do {                                                                              \
        const unsigned char* _q = bBase + (size_t)(S) * (16 * D_N);                   \
        _Pragma("unroll")                                                             \
        for (int ch = 0; ch < 4; ch++) {                                              \
            ((int4*)&BUF[ch])[0] = *(const int4*)(_q + (ch << 7));                    \
            ((int4*)&BUF[ch])[1] = *(const int4*)(_q + (ch << 7) + 16);               \
        }                                                                             \
    } while (0)

// One 16-col step: full K=512 reduction (16 MFMAs), then 16 exps into rs.
#define PHASE(BUF)                                                                    \
    do {                                                                              \
        floatx4 a0 = {0.f, 0.f, 0.f, 0.f}, a1 = {0.f, 0.f, 0.f, 0.f};                \
        floatx4 a2 = {0.f, 0.f, 0.f, 0.f}, a3 = {0.f, 0.f, 0.f, 0.f};                \
        __builtin_amdgcn_s_setprio(1);                                                \
        _Pragma("unroll")                                                             \
        for (int ch = 0; ch < 4; ch++) {                                              \
            a0 = mxfma(afr[ch][0], BUF[ch], a0);                                      \
            a1 = mxfma(afr[ch][1], BUF[ch], a1);                                      \
            a2 = mxfma(afr[ch][2], BUF[ch], a2);                                      \
            a3 = mxfma(afr[ch][3], BUF[ch], a3);                                      \
        }                                                                             \
        __builtin_amdgcn_s_setprio(0);                                                \
        _Pragma("unroll")                                                             \
        for (int r = 0; r < 4; r++) {                                                 \
            rs[r] += __expf(a0[r] * (INV_T / 256.0f));                                \
            rs[4 + r] += __expf(a1[r] * (INV_T / 256.0f));                            \
            rs[8 + r] += __expf(a2[r] * (INV_T / 256.0f));                            \
            rs[12 + r] += __expf(a3[r] * (INV_T / 256.0f));                           \
        }                                                                             \
    } while (0)

// ---- flash GEMM (MX-fp8, no LDS: A + streamed B all in registers):
//      rowsum[b] += sum_k exp(2*dot(emb_n[b], proto_n[k]))  ----
__global__ __launch_bounds__(256, 2) void flash_kernel(const unsigned char* __restrict__ embq,
                                                       const unsigned char* __restrict__ proq,
                                                       float* __restrict__ rowsum_g) {
    const int t = threadIdx.x;
    const int w = t >> 6, lane = t & 63;
    const int quad = lane >> 4, lcol = lane & 15;

    // XCD-pinned K-split: ks = b&15, XCD = b%8 -> splits {s, s+8} share XCD s%8,
    // 1 MB proq slice per XCD stays L2-resident (proven R13-R15 FETCH drop).
    const int ks = blockIdx.x & 15;                  // K-split 0..15
    const int band = blockIdx.x >> 4;                // 0..31: 256-row emb band
    const int rowBase = band * 256 + w * 64;         // wave owns 64 emb rows
    const int kb = ks * (K_N / KSPLIT);

    // A fragments: afr[ch][mi] = rows rowBase+mi*16+lcol, k-chunk ch, bytes
    // quad*32..+31 (MFMA A layout: lane=(lcol,quad) holds k=quad*32..+31).
    intx8 afr[4][4];
    {
        const unsigned char* aBase = embq + (size_t)(rowBase + lcol) * D_N + quad * 32;
        #pragma unroll
        for (int ch = 0; ch < 4; ch++)
            #pragma unroll
            for (int mi = 0; mi < 4; mi++) {
                const unsigned char* p = aBase + (size_t)mi * (16 * D_N) + (ch << 7);
                ((int4*)&afr[ch][mi])[0] = *(const int4*)(p);
                ((int4*)&afr[ch][mi])[1] = *(const int4*)(p + 16);
            }
    }

    // B stream base: lane=(lcol,quad) holds col n=lcol, k=quad*32..+31 (B layout
    // mirrors A); step S covers proto rows kb + S*16 .. +16.
    const unsigned char* bBase = proq + (size_t)(kb + lcol) * D_N + quad * 32;

    float rs[16];
    #pragma unroll
    for (int i = 0; i < 16; i++) rs[i] = 0.0f;

    intx8 bfA[4], bfB[4];
    LOADB(bfA, 0);
    for (int s = 0; s < NSTEP; s += 2) {
        if (s + 1 < NSTEP) LOADB(bfB, s + 1);  // prefetch under phase-A MFMAs
        PHASE(bfA);
        if (s + 2 < NSTEP) LOADB(bfA, s + 2);  // prefetch under phase-B MFMAs
        PHASE(bfB);
    }

    // C/D layout: col=lane&15, row=quad*4+r. rs[mi*4+r] = partial sum for emb row
    // rowBase + mi*16 + quad*4 + r over this lane's 64 cols; reduce over the 16
    // lcol lanes (xor 1/2/4/8 stays within the quad), one atomic per row.
    #pragma unroll
    for (int i = 0; i < 16; i++) {
        #pragma unroll
        for (int o = 1; o < 16; o <<= 1) rs[i] += __shfl_xor(rs[i], o);
    }
    if (lcol == 0) {
        #pragma unroll
        for (int mi = 0; mi < 4; mi++)
            #pragma unroll
            for (int r = 0; r < 4; r++)
                atomicAdd(&rowsum_g[rowBase + mi * 16 + quad * 4 + r], rs[mi * 4 + r]);
    }
}

// ---- loss partial: 32 blocks, atomicAdd into out[0]; also zero cnt for EMA. ----
__global__ void loss_kernel(const float* __restrict__ rowsum, const float* __restrict__ rowpos,
                            float* __restrict__ out, int* __restrict__ cnt) {
    __shared__ float red[256];
    int t = threadIdx.x;
    int b = blockIdx.x * 256 + t;
    cnt[b * 2] = 0;
    cnt[b * 2 + 1] = 0;
    float p = rowpos[b];
    red[t] = logf(rowsum[b] - __expf(p)) - p;
    __syncthreads();
    for (int o = 128; o; o >>= 1) {
        if (t < o) red[t] += red[t + o];
        __syncthreads();
    }
    if (t == 0) atomicAdd(out, red[0] * (1.0f / (float)B_N));
}

// ---- EMA phase 1: bucket occurrence indices per cluster. ----
__global__ void ema_count(const int* __restrict__ cid, int* __restrict__ cnt,
                          int* __restrict__ bucket) {
    int b = blockIdx.x * 256 + threadIdx.x;
    int c = cid[b];
    int slot = atomicAdd(&cnt[c], 1);
    if (slot < CAP) bucket[c * CAP + slot] = b;
}

// ---- EMA phase 2: one wave per cluster, replay occurrences in ascending b. ----
__global__ void ema_apply(const float* __restrict__ emb, const float* __restrict__ pro,
                          const int* __restrict__ cnt, const int* __restrict__ bucket,
                          float* __restrict__ outp) {
    int k = blockIdx.x * 4 + (threadIdx.x >> 6);
    int lane = threadIdx.x & 63;
    int n = cnt[k];
    n = n < CAP ? n : CAP;
    const float4* pp = (const float4*)(pro + (size_t)k * D_N + lane * 8);
    float4 a0 = pp[0], a1 = pp[1];
    int myb = (lane < n) ? bucket[k * CAP + lane] : 0x7fffffff;
    for (int i = 0; i < n; i++) {
        int m = myb;
        #pragma unroll
        for (int o = 1; o < 64; o <<= 1) {
            int v = __shfl_xor(m, o);
            m = v < m ? v : m;
        }
        const float4* ep = (const float4*)(emb + (size_t)m * D_N + lane * 8);
        float4 e0 = ep[0], e1 = ep[1];
        a0.x = MOM * a0.x + (1.0f - MOM) * e0.x;
        a0.y = MOM * a0.y + (1.0f - MOM) * e0.y;
        a0.z = MOM * a0.z + (1.0f - MOM) * e0.z;
        a0.w = MOM * a0.w + (1.0f - MOM) * e0.w;
        a1.x = MOM * a1.x + (1.0f - MOM) * e1.x;
        a1.y = MOM * a1.y + (1.0f - MOM) * e1.y;
        a1.z = MOM * a1.z + (1.0f - MOM) * e1.z;
        a1.w = MOM * a1.w + (1.0f - MOM) * e1.w;
        if (myb == m) myb = 0x7fffffff;
    }
    float4* op = (float4*)(outp + (size_t)k * D_N + lane * 8);
    op[0] = a0;
    op[1] = a1;
}

extern "C" void kernel_launch(void* const* d_in, const int* in_sizes, int n_in,
                              void* d_out, int out_size, void* d_ws, size_t ws_size,
                              hipStream_t stream) {
    const float* emb = (const float*)d_in[0];
    const int* cid = (const int*)d_in[1];
    const float* pro = (const float*)d_in[2];
    float* out = (float*)d_out;

    char* ws = (char*)d_ws;
    unsigned char* embq = (unsigned char*)ws;                      // 4 MB fp8 [B,D]
    unsigned char* proq = (unsigned char*)(ws + 4194304);          // 8 MB fp8 [K,D]
    float* rowsum = (float*)(ws + 12582912);                       // [B]
    float* rowpos = (float*)(ws + 12615680);                       // [B]
    // EMA buckets alias the proq region — only touched after flash_kernel (stream
    // order): loss_kernel zeroes cnt, ema_count fills, ema_apply reads.
    int* cnt = (int*)(ws + 4194304);                               // [K]
    int* bucket = (int*)(ws + 4194304 + 65536);                    // [K, CAP]

    norm_kernel<<<(B_N + K_N) / 4, 256, 0, stream>>>(emb, pro, embq, proq, rowsum, out);
    pos_kernel<<<B_N / 4, 256, 0, stream>>>(emb, pro, cid, rowpos);
    flash_kernel<<<dim3(32 * KSPLIT), 256, 0, stream>>>(embq, proq, rowsum);
    loss_kernel<<<B_N / 256, 256, 0, stream>>>(rowsum, rowpos, out, cnt);
    ema_count<<<B_N / 256, 256, 0, stream>>>(cid, cnt, bucket);
    ema_apply<<<K_N / 4, 256, 0, stream>>>(emb, pro, cnt, bucket, out + 1);
}